// Round 1
// baseline (259.528 us; speedup 1.0000x reference)
//
#include <hip/hip_runtime.h>

// Problem constants (from reference setup_inputs):
// B=2, I=63, H=W=320, HID=128, C=14, DOWN=4, h4=w4=80
#define NB 2
#define NI 63
#define BI (NB*NI)          // 126
#define HW 320
#define HWF (HW*HW)         // 102400 pixels per (b,i)
#define H4 80
#define HW4 (H4*H4)         // 6400
#define HID 128
#define IFM_B (HID*HW4)     // 819200 floats per batch

#define OUT_DEPTH 0
#define OUT_CAN   (BI*HWF)            // 12902400
#define OUT_SCALE (2*BI*HWF)          // 25804800
#define OUT_SHIFT (2*BI*HWF + BI)     // 25804926

// ---------------------------------------------------------------------------
// Kernel A: can_small[b,hw] = sum_c ifm[b,c,hw]*Wc[c] + bc   (2*6400 outputs)
// ---------------------------------------------------------------------------
__global__ __launch_bounds__(256) void can_kernel(
    const float* __restrict__ ifm, const float* __restrict__ Wc,
    const float* __restrict__ bc, float* __restrict__ can_ws) {
  int g = blockIdx.x * 256 + threadIdx.x;   // 0..12799
  if (g >= NB * HW4) return;
  int b = g / HW4, hw = g % HW4;
  const float* base = ifm + b * IFM_B + hw;
  float acc = bc[0];
#pragma unroll 8
  for (int c = 0; c < HID; ++c) acc += base[c * HW4] * Wc[c];
  can_ws[g] = acc;
}

// ---------------------------------------------------------------------------
// Kernel B: per (b,i): pooled[c] = sum_hw m_ds*ifm; scale/shift via labels.
// One block of 256 threads per (b,i). m_ds staged in LDS (25.6 KB).
// ---------------------------------------------------------------------------
__global__ __launch_bounds__(256) void pool_kernel(
    const int* __restrict__ inst, const float* __restrict__ ifm,
    const int* __restrict__ labels,
    const float* __restrict__ W_scale, const float* __restrict__ b_scale,
    const float* __restrict__ W_shift, const float* __restrict__ b_shift,
    float* __restrict__ scale_out, float* __restrict__ shift_out) {
  __shared__ float m_lds[HW4];
  __shared__ float pooled[HID];
  __shared__ float red[4];

  int bi = blockIdx.x;          // 0..125
  int b = bi / NI;
  int t = threadIdx.x;
  int wave = t >> 6, lane = t & 63;

  // Phase 1: downsampled mask -> LDS, and its sum.
  const int* ibase = inst + (long)bi * HWF;
  float msum_local = 0.f;
#pragma unroll
  for (int j = 0; j < HW4 / 256; ++j) {       // 25 iters
    int hw = t + 256 * j;
    int r = hw / H4, col = hw - r * H4;
    float v = (float)ibase[r * (4 * HW) + col * 4];
    m_lds[hw] = v;
    msum_local += v;
  }
  for (int off = 32; off; off >>= 1) msum_local += __shfl_down(msum_local, off, 64);
  if (lane == 0) red[wave] = msum_local;
  __syncthreads();
  float msum = red[0] + red[1] + red[2] + red[3];

  // Phase 2: pooled[c] — wave w handles channels [w*32, w*32+32), float4 stream.
  const float* fbase = ifm + (long)b * IFM_B;
  const float4* ml = (const float4*)m_lds;
  for (int k = 0; k < 32; ++k) {
    int c = wave * 32 + k;
    const float4* fc = (const float4*)(fbase + c * HW4);
    float acc = 0.f;
#pragma unroll 5
    for (int j = lane; j < HW4 / 4; j += 64) {  // 25 iters of float4
      float4 f = fc[j];
      float4 m = ml[j];
      acc += f.x * m.x + f.y * m.y + f.z * m.z + f.w * m.w;
    }
    for (int off = 32; off; off >>= 1) acc += __shfl_down(acc, off, 64);
    if (lane == 0) pooled[c] = acc;
  }
  __syncthreads();

  // Phase 3: scale/shift on wave 0 (lane handles channels lane and lane+64).
  if (wave == 0) {
    int lab = labels[bi];
    float valid = (lab != 0) ? 1.f : 0.f;
    float inv = 1.f / fmaxf(msum, 1.f);
    float p0 = pooled[lane], p1 = pooled[lane + 64];
    const float* ws = W_scale + lab * HID;
    const float* wh = W_shift + lab * HID;
    float sa = p0 * ws[lane] + p1 * ws[lane + 64];
    float sh = p0 * wh[lane] + p1 * wh[lane + 64];
    for (int off = 32; off; off >>= 1) {
      sa += __shfl_down(sa, off, 64);
      sh += __shfl_down(sh, off, 64);
    }
    if (lane == 0) {
      scale_out[bi] = (sa * inv + b_scale[lab]) * valid;
      shift_out[bi] = (sh * inv + b_shift[lab]) * valid;
    }
  }
}

// ---------------------------------------------------------------------------
// Kernel C: full-res outputs. 1024 contiguous pixels per block (100 blocks per
// (b,i) image). Each thread: int4 mask load, 2x float4 stores.
// 4 consecutive pixels (4-aligned) share one can_small value.
// ---------------------------------------------------------------------------
__global__ __launch_bounds__(256) void out_kernel(
    const int* __restrict__ inst, const float* __restrict__ can_ws,
    const int* __restrict__ labels,
    const float* __restrict__ scale_arr, const float* __restrict__ shift_arr,
    float* __restrict__ out_depth, float* __restrict__ out_can) {
  int blk = blockIdx.x;          // 0..12599
  int bi = blk / 100;
  int chunk = blk - bi * 100;
  int b = bi / NI;
  int pix = chunk * 1024 + threadIdx.x * 4;
  int h = pix / HW, w = pix - h * HW;   // all 4 pixels in same row (320%4==0)

  float can = can_ws[b * HW4 + (h >> 2) * H4 + (w >> 2)];
  int lab = labels[bi];
  float valid = (lab != 0) ? 1.f : 0.f;
  float sc = scale_arr[bi];
  float sh = shift_arr[bi];
  float cv = can * valid;

  long base = (long)bi * HWF + pix;
  const int4 iv = *(const int4*)(inst + base);
  float4 cf, df;
  cf.x = cv * (float)iv.x;
  cf.y = cv * (float)iv.y;
  cf.z = cv * (float)iv.z;
  cf.w = cv * (float)iv.w;
  df.x = fmaxf(cf.x * sc + sh, 0.001f);
  df.y = fmaxf(cf.y * sc + sh, 0.001f);
  df.z = fmaxf(cf.z * sc + sh, 0.001f);
  df.w = fmaxf(cf.w * sc + sh, 0.001f);
  *(float4*)(out_can + base) = cf;
  *(float4*)(out_depth + base) = df;
}

// ---------------------------------------------------------------------------
extern "C" void kernel_launch(void* const* d_in, const int* in_sizes, int n_in,
                              void* d_out, int out_size, void* d_ws, size_t ws_size,
                              hipStream_t stream) {
  // Input order per setup_inputs dict:
  // 0 depth, 1 context, 2 input_feature_map, 3 bin_num, 4 min_depth,
  // 5 max_depth, 6 masks, 7 instances, 8 boxes, 9 labels,
  // 10 W_scale, 11 b_scale, 12 W_shift, 13 b_shift, 14 Wc, 15 bc
  const float* ifm     = (const float*)d_in[2];
  const int*   inst    = (const int*)d_in[7];
  const int*   labels  = (const int*)d_in[9];
  const float* W_scale = (const float*)d_in[10];
  const float* b_scale = (const float*)d_in[11];
  const float* W_shift = (const float*)d_in[12];
  const float* b_shift = (const float*)d_in[13];
  const float* Wc      = (const float*)d_in[14];
  const float* bc      = (const float*)d_in[15];

  float* out       = (float*)d_out;
  float* out_depth = out + OUT_DEPTH;
  float* out_can   = out + OUT_CAN;
  float* out_scale = out + OUT_SCALE;
  float* out_shift = out + OUT_SHIFT;
  float* can_ws    = (float*)d_ws;   // 2*6400 floats = 51.2 KB

  can_kernel<<<(NB * HW4 + 255) / 256, 256, 0, stream>>>(ifm, Wc, bc, can_ws);
  pool_kernel<<<BI, 256, 0, stream>>>(inst, ifm, labels, W_scale, b_scale,
                                      W_shift, b_shift, out_scale, out_shift);
  out_kernel<<<BI * 100, 256, 0, stream>>>(inst, can_ws, labels, out_scale,
                                           out_shift, out_depth, out_can);
}

// Round 2
// 205.185 us; speedup vs baseline: 1.2649x; 1.2649x over previous
//
#include <hip/hip_runtime.h>

// Problem constants (from reference setup_inputs):
// B=2, I=63, H=W=320, HID=128, C=14, DOWN=4, h4=w4=80
#define NB 2
#define NI 63
#define BI (NB*NI)          // 126
#define HW 320
#define HWF (HW*HW)         // 102400 pixels per (b,i)
#define H4 80
#define HW4 (H4*H4)         // 6400
#define HID 128
#define IFM_B (HID*HW4)     // 819200 floats per batch

#define OUT_DEPTH 0
#define OUT_CAN   (BI*HWF)            // 12902400
#define OUT_SCALE (2*BI*HWF)          // 25804800
#define OUT_SHIFT (2*BI*HWF + BI)     // 25804926

// Pool-GEMM tiling
#define KB 128              // hw4 positions per block
#define NKB (HW4/KB)        // 50 blocks per batch
#define FPAD 132            // fT/mT padded row stride (floats)
#define PROW 132            // partial row stride per i (129 used)
#define PBLK (64*PROW)      // per-block partial floats (8448)

// ---------------------------------------------------------------------------
// Kernel P: per (b, k-chunk of 128 hw4):
//   - stage fT[c][k] (128x128 ifm tile) and mT[i][k] (64x128 mask tile) in LDS
//   - GEMM: partial[i][c] = sum_k mT[i][k]*fT[c][k]  (register-tiled 4i x 8c)
//   - msum partial per i  -> partial[i][128]
//   - can_small for these 128 hw: sum_c fT[c][j]*Wc[c] + bc -> can_ws
// Reads ifm exactly once across the grid.
// ---------------------------------------------------------------------------
__global__ __launch_bounds__(256) void pool_gemm_kernel(
    const int* __restrict__ inst, const float* __restrict__ ifm,
    const float* __restrict__ Wc, const float* __restrict__ bc,
    float* __restrict__ can_ws, float* __restrict__ partial) {
  __shared__ float fT[128][FPAD];   // 67.6 KB
  __shared__ float mT[64][FPAD];    // 33.8 KB
  __shared__ float wc_s[128];

  int bid = blockIdx.x;             // 0..99
  int b = bid / NKB, kb = bid % NKB;
  int k0 = kb * KB;                 // base hw4 for this chunk
  int t = threadIdx.x;

  if (t < 128) wc_s[t] = Wc[t];

  // ---- stage fT: 128 c x 128 k floats, coalesced float4 global reads ----
  const float* fbase = ifm + (long)b * IFM_B;
#pragma unroll
  for (int s = 0; s < 16; ++s) {
    int v = s * 256 + t;            // 0..4095 float4 slots
    int c = v >> 5;                 // 32 float4 per row
    int jq = v & 31;
    float4 x = *(const float4*)(fbase + c * HW4 + k0 + jq * 4);
    *(float4*)&fT[c][jq * 4] = x;
  }
  // ---- stage mT: 64 i x 128 k (row 63 zero-padded) ----
#pragma unroll
  for (int s = 0; s < 32; ++s) {
    int v = s * 256 + t;            // 0..8191
    int i = v >> 7;
    int j = v & 127;
    int hw4 = k0 + j;
    int r = hw4 / H4, col = hw4 - r * H4;
    float m = 0.f;
    if (i < NI) m = (float)inst[((long)(b * NI + i)) * HWF + r * 4 * HW + col * 4];
    mT[i][j] = m;
  }
  __syncthreads();

  // ---- register-tiled GEMM: thread (ti,tc) -> i in [4ti,4ti+4), c = tc+16v ----
  int ti = t >> 4, tc = t & 15;
  int i0 = ti * 4;
  float acc[4][8];
#pragma unroll
  for (int u = 0; u < 4; ++u)
#pragma unroll
    for (int v = 0; v < 8; ++v) acc[u][v] = 0.f;

  for (int k = 0; k < KB; k += 4) {
    float4 a[4], bb[8];
#pragma unroll
    for (int u = 0; u < 4; ++u) a[u] = *(const float4*)&mT[i0 + u][k];
#pragma unroll
    for (int v = 0; v < 8; ++v) bb[v] = *(const float4*)&fT[tc + 16 * v][k];
#pragma unroll
    for (int u = 0; u < 4; ++u)
#pragma unroll
      for (int v = 0; v < 8; ++v)
        acc[u][v] += a[u].x * bb[v].x + a[u].y * bb[v].y +
                     a[u].z * bb[v].z + a[u].w * bb[v].w;
  }

  // ---- write partials: c = tc + 16v (lanes contiguous in tc -> coalesced) ----
  float* pb = partial + (long)bid * PBLK;
#pragma unroll
  for (int u = 0; u < 4; ++u)
#pragma unroll
    for (int v = 0; v < 8; ++v)
      pb[(i0 + u) * PROW + tc + 16 * v] = acc[u][v];

  // ---- msum partial per i: threads 0..63 sum their mT row ----
  if (t < 64) {
    float ms = 0.f;
#pragma unroll
    for (int q = 0; q < KB / 4; ++q) {
      float4 m4 = *(const float4*)&mT[t][q * 4];
      ms += m4.x + m4.y + m4.z + m4.w;
    }
    pb[t * PROW + 128] = ms;
  }

  // ---- can_small for these 128 hw: threads 0..127, column read of fT ----
  if (t < 128) {
    float ca = bc[0];
#pragma unroll 8
    for (int c = 0; c < 128; ++c) ca += fT[c][t] * wc_s[c];
    can_ws[b * HW4 + k0 + t] = ca;
  }
}

// ---------------------------------------------------------------------------
// Kernel F: per (b,i): reduce 50 partials -> pooled[c], msum; then
// scale/shift via labels. 126 blocks x 128 threads.
// ---------------------------------------------------------------------------
__global__ __launch_bounds__(128) void finish_kernel(
    const float* __restrict__ partial, const int* __restrict__ labels,
    const float* __restrict__ W_scale, const float* __restrict__ b_scale,
    const float* __restrict__ W_shift, const float* __restrict__ b_shift,
    float* __restrict__ scale_out, float* __restrict__ shift_out) {
  __shared__ float pooled[128];
  __shared__ float msum_s;

  int bi = blockIdx.x;            // 0..125
  int b = bi / NI, i = bi % NI;
  int t = threadIdx.x;            // 0..127
  int lane = t & 63;

  const float* pb = partial + ((long)b * NKB) * PBLK + i * PROW;

  float acc = 0.f;
#pragma unroll 5
  for (int kb = 0; kb < NKB; ++kb) acc += pb[(long)kb * PBLK + t];
  pooled[t] = acc;

  // msum: wave 0 lanes 0..49 each grab one chunk's partial, shuffle-reduce
  if (t < 64) {
    float ms = (t < NKB) ? pb[(long)t * PBLK + 128] : 0.f;
    for (int off = 32; off; off >>= 1) ms += __shfl_down(ms, off, 64);
    if (t == 0) msum_s = ms;
  }
  __syncthreads();

  if (t < 64) {
    int lab = labels[bi];
    float valid = (lab != 0) ? 1.f : 0.f;
    float inv = 1.f / fmaxf(msum_s, 1.f);
    float p0 = pooled[lane], p1 = pooled[lane + 64];
    const float* ws = W_scale + lab * HID;
    const float* wh = W_shift + lab * HID;
    float sa = p0 * ws[lane] + p1 * ws[lane + 64];
    float sh = p0 * wh[lane] + p1 * wh[lane + 64];
    for (int off = 32; off; off >>= 1) {
      sa += __shfl_down(sa, off, 64);
      sh += __shfl_down(sh, off, 64);
    }
    if (lane == 0) {
      scale_out[bi] = (sa * inv + b_scale[lab]) * valid;
      shift_out[bi] = (sh * inv + b_shift[lab]) * valid;
    }
  }
}

// ---------------------------------------------------------------------------
// Kernel C: full-res outputs. 1024 contiguous pixels per block (100 blocks per
// (b,i) image). Each thread: int4 mask load, 2x float4 stores.
// ---------------------------------------------------------------------------
__global__ __launch_bounds__(256) void out_kernel(
    const int* __restrict__ inst, const float* __restrict__ can_ws,
    const int* __restrict__ labels,
    const float* __restrict__ scale_arr, const float* __restrict__ shift_arr,
    float* __restrict__ out_depth, float* __restrict__ out_can) {
  int blk = blockIdx.x;          // 0..12599
  int bi = blk / 100;
  int chunk = blk - bi * 100;
  int b = bi / NI;
  int pix = chunk * 1024 + threadIdx.x * 4;
  int h = pix / HW, w = pix - h * HW;   // all 4 pixels in same row (320%4==0)

  float can = can_ws[b * HW4 + (h >> 2) * H4 + (w >> 2)];
  int lab = labels[bi];
  float valid = (lab != 0) ? 1.f : 0.f;
  float sc = scale_arr[bi];
  float sh = shift_arr[bi];
  float cv = can * valid;

  long base = (long)bi * HWF + pix;
  const int4 iv = *(const int4*)(inst + base);
  float4 cf, df;
  cf.x = cv * (float)iv.x;
  cf.y = cv * (float)iv.y;
  cf.z = cv * (float)iv.z;
  cf.w = cv * (float)iv.w;
  df.x = fmaxf(cf.x * sc + sh, 0.001f);
  df.y = fmaxf(cf.y * sc + sh, 0.001f);
  df.z = fmaxf(cf.z * sc + sh, 0.001f);
  df.w = fmaxf(cf.w * sc + sh, 0.001f);
  *(float4*)(out_can + base) = cf;
  *(float4*)(out_depth + base) = df;
}

// ---------------------------------------------------------------------------
extern "C" void kernel_launch(void* const* d_in, const int* in_sizes, int n_in,
                              void* d_out, int out_size, void* d_ws, size_t ws_size,
                              hipStream_t stream) {
  // Input order per setup_inputs dict:
  // 0 depth, 1 context, 2 input_feature_map, 3 bin_num, 4 min_depth,
  // 5 max_depth, 6 masks, 7 instances, 8 boxes, 9 labels,
  // 10 W_scale, 11 b_scale, 12 W_shift, 13 b_shift, 14 Wc, 15 bc
  const float* ifm     = (const float*)d_in[2];
  const int*   inst    = (const int*)d_in[7];
  const int*   labels  = (const int*)d_in[9];
  const float* W_scale = (const float*)d_in[10];
  const float* b_scale = (const float*)d_in[11];
  const float* W_shift = (const float*)d_in[12];
  const float* b_shift = (const float*)d_in[13];
  const float* Wc      = (const float*)d_in[14];
  const float* bc      = (const float*)d_in[15];

  float* out       = (float*)d_out;
  float* out_depth = out + OUT_DEPTH;
  float* out_can   = out + OUT_CAN;
  float* out_scale = out + OUT_SCALE;
  float* out_shift = out + OUT_SHIFT;

  float* can_ws  = (float*)d_ws;               // 12800 floats (51.2 KB)
  float* partial = (float*)d_ws + 2 * HW4;     // 100*8448 floats (3.38 MB)

  pool_gemm_kernel<<<NB * NKB, 256, 0, stream>>>(inst, ifm, Wc, bc,
                                                 can_ws, partial);
  finish_kernel<<<BI, 128, 0, stream>>>(partial, labels, W_scale, b_scale,
                                        W_shift, b_shift, out_scale, out_shift);
  out_kernel<<<BI * 100, 256, 0, stream>>>(inst, can_ws, labels, out_scale,
                                           out_shift, out_depth, out_can);
}